// Round 1
// 194.610 us; speedup vs baseline: 1.0947x; 1.0947x over previous
//
#include <hip/hip_runtime.h>

// ContourIntegrationLayer: depthwise 3x3 conv, center tap masked to 0,
// SAME padding, + residual. x: [B,H,W,C] fp32 NHWC, kernel: [3,3,C] fp32.
// B=32 H=56 W=56 C=256.
//
// R1: XCD-aware block swizzle (kept).
// R2: vertical rolling window. Each thread owns a column strip of P=14
// consecutive output rows at fixed (b,w,c4). The 3x3 window lives in
// registers; per output row we load only the 3 vectors of the incoming row
// and rotate. Loads/output: 17 -> ~4 (kernel taps amortized 8/14, x rows
// reused 3x vertically). Attacks the L1/VMEM pipe (prev: 1.75 GB through L1
// at ~18.7 TB/s while HBM sat at 20%).

#define BB 32
#define HH 56
#define WW 56
#define CC 256
#define C4 (CC / 4)      // 64 float4 groups per pixel
#define NXCD 8
#define P 14             // output rows per thread (56 = 4*14)
#define NHC (HH / P)     // 4 h-chunks
#define ROWSTR (WW * C4) // float4 stride between image rows = 3584

#define FMA4(acc, v, k)          \
    acc.x += (v).x * (k).x;      \
    acc.y += (v).y * (k).y;      \
    acc.z += (v).z * (k).z;      \
    acc.w += (v).w * (k).w;

__global__ __launch_bounds__(256, 4) void contour_kernel(
    const float4* __restrict__ x,     // [B*H*W*C4]
    const float4* __restrict__ kern,  // [9*C4]
    float4* __restrict__ out)         // [B*H*W*C4]
{
    // XCD swizzle: hardware assigns blockIdx.x -> XCD (blockIdx.x % 8).
    // Remap so XCD k processes a contiguous chunk (4 whole images).
    const int nblocks = gridDim.x;          // 1792, divisible by 8
    const int per_xcd = nblocks / NXCD;     // 224
    const int xcd     = blockIdx.x % NXCD;
    const int local   = blockIdx.x / NXCD;
    const int blk     = xcd * per_xcd + local;

    int idx = blk * blockDim.x + threadIdx.x;
    int c4 = idx & (C4 - 1);
    int s  = idx >> 6;            // strip index: ((b*NHC + hc)*WW + w)
    int w  = s % WW;
    int t  = s / WW;
    int hc = t & (NHC - 1);
    int b  = t >> 2;              // NHC == 4
    if (b >= BB) return;

    const float4 zero = make_float4(0.f, 0.f, 0.f, 0.f);

    // Kernel taps (tap 4 = center is masked out). Hit L1 after first block.
    const float4* kp = kern + c4;
    float4 k0 = kp[0 * C4], k1 = kp[1 * C4], k2 = kp[2 * C4];
    float4 k3 = kp[3 * C4],                  k5 = kp[5 * C4];
    float4 k6 = kp[6 * C4], k7 = kp[7 * C4], k8 = kp[8 * C4];

    const int h0 = hc * P;
    const float4* xb = x   + (size_t)(b * HH) * ROWSTR + w * C4 + c4;
    float4*       ob = out + (size_t)(b * HH) * ROWSTR + w * C4 + c4;

    const bool wl = (w > 0);        // wave-uniform
    const bool wr = (w < WW - 1);   // wave-uniform

    // Rolling 3-row window: a = row h-1, r = row h, c = row h+1.
    float4 a0, a1, a2, r0, r1, r2, c0, c1, c2;

    auto loadrow = [&](int hh, float4& L, float4& Cv, float4& R) {
        if (hh < 0 || hh >= HH) { L = zero; Cv = zero; R = zero; return; }
        const float4* p = xb + hh * ROWSTR;
        Cv = p[0];
        L  = wl ? p[-C4] : zero;
        R  = wr ? p[ C4] : zero;
    };

    loadrow(h0 - 1, a0, a1, a2);
    loadrow(h0,     r0, r1, r2);

    #pragma unroll
    for (int i = 0; i < P; ++i) {
        const int h = h0 + i;
        loadrow(h + 1, c0, c1, c2);

        float4 acc = r1;            // residual add (center pixel)
        FMA4(acc, a0, k0); FMA4(acc, a1, k1); FMA4(acc, a2, k2);  // row h-1
        FMA4(acc, r0, k3);                    FMA4(acc, r2, k5);  // row h (no center)
        FMA4(acc, c0, k6); FMA4(acc, c1, k7); FMA4(acc, c2, k8);  // row h+1

        ob[h * ROWSTR] = acc;

        a0 = r0; a1 = r1; a2 = r2;
        r0 = c0; r1 = c1; r2 = c2;
    }
}

extern "C" void kernel_launch(void* const* d_in, const int* in_sizes, int n_in,
                              void* d_out, int out_size, void* d_ws, size_t ws_size,
                              hipStream_t stream) {
    const float4* x    = (const float4*)d_in[0];
    const float4* kern = (const float4*)d_in[1];
    float4* out        = (float4*)d_out;

    const int total = BB * NHC * WW * C4;           // 458,752 threads
    const int block = 256;
    const int grid  = (total + block - 1) / block;  // 1792 blocks (8*224)
    contour_kernel<<<grid, block, 0, stream>>>(x, kern, out);
}